// Round 4
// baseline (320.439 us; speedup 1.0000x reference)
//
#include <hip/hip_runtime.h>
#include <hip/hip_bf16.h>

// ConvSelfAttn: B=8, N=4096, C=64, d=8. FP32 I/O.
// R4: occupancy push. attn: 1024 blocks x 512 thr (2 qsub x 4 key-split),
// deferred-l softmax (no per-iter cross-lane sum), hoisted zero-init,
// launch_bounds(512,6). proj: weights staged in LDS (coalesced), frags via
// ds_read_b128.

#define BB 8
#define NN 4096
#define CC 64
#define PSTRIDE 72

typedef _Float16 f16;
typedef _Float16 half8 __attribute__((ext_vector_type(8)));
typedef _Float16 half4 __attribute__((ext_vector_type(4)));
typedef float floatx4 __attribute__((ext_vector_type(4)));

// ---------------- fused projection (MFMA): Q,K,V^T ----------------
// grid 512 x 256 (4 waves x 16 pixels). Weights staged in LDS once per block.
__global__ __launch_bounds__(256) void proj_all_kernel(
    const float* __restrict__ x,
    const float* __restrict__ wq, const float* __restrict__ bq,
    const float* __restrict__ wk, const float* __restrict__ bk,
    const float* __restrict__ wv, const float* __restrict__ bv,
    f16* __restrict__ Qh, f16* __restrict__ Kh, f16* __restrict__ VT)
{
    __shared__ alignas(16) f16 Ws[80][PSTRIDE];  // [cout][cin], rows 0-63=V,64-71=Q,72-79=K
    __shared__ float Bs[80];
    const int tid = threadIdx.x;

    for (int i = tid; i < 4096; i += 256) {         // wv coalesced
        int cin = i >> 6, cout = i & 63;
        Ws[cout][cin] = (f16)wv[i];
    }
    for (int i = tid; i < 512; i += 256) {          // wq/wk coalesced
        int cin = i >> 3, c = i & 7;
        Ws[64 + c][cin] = (f16)wq[i];
        Ws[72 + c][cin] = (f16)wk[i];
    }
    if (tid < 80) Bs[tid] = (tid < 64) ? bv[tid] : (tid < 72 ? bq[tid - 64] : bk[tid - 72]);
    __syncthreads();

    const int wave = tid >> 6, lane = tid & 63;
    const int quad = lane >> 4, n16 = lane & 15;
    const long p0 = (long)blockIdx.x * 64 + wave * 16;

    // x A-frags: A[m=pixel=n16][k=cin=kh*32+quad*8+j]
    half8 ax[2];
#pragma unroll
    for (int kh = 0; kh < 2; ++kh) {
        const float* xp = x + (p0 + n16) * 64 + kh * 32 + quad * 8;
        float4 x1 = *(const float4*)xp;
        float4 x2 = *(const float4*)(xp + 4);
        ax[kh][0] = (f16)x1.x; ax[kh][1] = (f16)x1.y;
        ax[kh][2] = (f16)x1.z; ax[kh][3] = (f16)x1.w;
        ax[kh][4] = (f16)x2.x; ax[kh][5] = (f16)x2.y;
        ax[kh][6] = (f16)x2.z; ax[kh][7] = (f16)x2.w;
    }

    const int b   = (int)(p0 >> 12);
    const int nn0 = (int)(p0 & 4095);
#pragma unroll
    for (int ct = 0; ct < 5; ++ct) {
        const int cout = (ct < 4) ? ct * 16 + n16 : 64 + n16;
        const float bias = Bs[cout];
        half8 b0 = *(const half8*)(&Ws[cout][quad * 8]);
        half8 b1 = *(const half8*)(&Ws[cout][32 + quad * 8]);
        floatx4 acc = {bias, bias, bias, bias};
        acc = __builtin_amdgcn_mfma_f32_16x16x32_f16(ax[0], b0, acc, 0, 0, 0);
        acc = __builtin_amdgcn_mfma_f32_16x16x32_f16(ax[1], b1, acc, 0, 0, 0);
        if (ct < 4) {
            half4 pk;
#pragma unroll
            for (int r = 0; r < 4; ++r) pk[r] = (f16)acc[r];
            *(half4*)(VT + ((size_t)(b * 64 + ct * 16 + n16)) * NN + nn0 + quad * 4) = pk;
        } else {
            f16* dst = (n16 < 8) ? (Qh + (p0 + quad * 4) * 8 + n16)
                                 : (Kh + (p0 + quad * 4) * 8 + (n16 - 8));
#pragma unroll
            for (int r = 0; r < 4; ++r) dst[r * 8] = (f16)acc[r];
        }
    }
}

// ---------------- flash attention, S^T form, key-split 4 ----------------
// grid B*128 = 1024 x 512 thr; wave: qsub = wave&1 (16 queries), ks = wave>>1
// (1024 keys, 16 iterations). Merge 4 partials via LDS at end.
__global__ __launch_bounds__(512, 6) void attn_kernel(
    const f16* __restrict__ Qh, const f16* __restrict__ Kh,
    const f16* __restrict__ VT,
    const float* __restrict__ x, const float* __restrict__ gptr,
    float* __restrict__ out)
{
    __shared__ alignas(16) f16 Pbuf[8 * 16 * PSTRIDE];   // 18.4 KB
    __shared__ alignas(16) f16 Obuf[2][3][64][16];       // 12.3 KB
    __shared__ float MLs[2][4][16][2];                   // 1 KB

    const int tid  = threadIdx.x;
    const int wave = tid >> 6, lane = tid & 63;
    const int quad = lane >> 4, n16 = lane & 15;
    const int qsub = wave & 1, ks = wave >> 1;

    const int b  = blockIdx.x >> 7;
    const int qt = blockIdx.x & 127;
    const int q  = qt * 32 + qsub * 16 + n16;
    const size_t bN = (size_t)b * NN;

    // Q B-frag (quad0 only; zeros persist in other quads)
    half8 bq8;
#pragma unroll
    for (int j = 0; j < 8; ++j) bq8[j] = (f16)0.f;
    if (quad == 0) bq8 = *(const half8*)(Qh + (bN + q) * 8);

    half8 ak[4];
#pragma unroll
    for (int t = 0; t < 4; ++t)
#pragma unroll
        for (int j = 0; j < 8; ++j) ak[t][j] = (f16)0.f;

    floatx4 oacc[4];
#pragma unroll
    for (int ct = 0; ct < 4; ++ct) oacc[ct] = (floatx4){0.f, 0.f, 0.f, 0.f};
    float m_run = -1e30f, l_loc = 0.f;

    const f16* kptr  = Kh + (bN + (size_t)ks * 1024) * 8;
    const f16* vbase = VT + (size_t)b * 64 * NN + (size_t)ks * 1024;
    const floatx4 zero4 = {0.f, 0.f, 0.f, 0.f};
    f16* Pw = Pbuf + wave * 16 * PSTRIDE;

    for (int it = 0; it < 16; ++it) {
        const int k0 = it * 64;
        // first V half: issued early, consumed after softmax
        half8 av0[4];
#pragma unroll
        for (int ct = 0; ct < 4; ++ct)
            av0[ct] = *(const half8*)(vbase + (size_t)(ct * 16 + n16) * NN + k0 + quad * 8);
        // K tile (quad0 lanes only; other quads keep zeros)
        if (quad == 0) {
#pragma unroll
            for (int t = 0; t < 4; ++t)
                ak[t] = *(const half8*)(kptr + (k0 + t * 16 + n16) * 8);
        }
        // S^T = K Q^T: D[m=key=quad*4+r(+16t)][n=query=n16]
        floatx4 sf[4];
#pragma unroll
        for (int t = 0; t < 4; ++t)
            sf[t] = __builtin_amdgcn_mfma_f32_16x16x32_f16(ak[t], bq8, zero4, 0, 0, 0);
        // second V half: issue under softmax
        half8 av1[4];
#pragma unroll
        for (int ct = 0; ct < 4; ++ct)
            av1[ct] = *(const half8*)(vbase + (size_t)(ct * 16 + n16) * NN + k0 + 32 + quad * 8);

        // online softmax; l kept per-lane (exact: alpha is uniform across the
        // 4 lanes sharing a query, and l evolves linearly)
        float mx = sf[0][0];
#pragma unroll
        for (int t = 0; t < 4; ++t)
#pragma unroll
            for (int r = 0; r < 4; ++r) mx = fmaxf(mx, sf[t][r]);
        mx = fmaxf(mx, __shfl_xor(mx, 16, 64));
        mx = fmaxf(mx, __shfl_xor(mx, 32, 64));
        const float mnew = fmaxf(m_run, mx);
        const float alpha = __expf(m_run - mnew);
        m_run = mnew;
        float rs = 0.f;
#pragma unroll
        for (int t = 0; t < 4; ++t)
#pragma unroll
            for (int r = 0; r < 4; ++r) {
                float pv = __expf(sf[t][r] - mnew);
                sf[t][r] = pv;
                rs += pv;
            }
        l_loc = l_loc * alpha + rs;
#pragma unroll
        for (int ct = 0; ct < 4; ++ct) oacc[ct] *= alpha;

        // P^T -> per-wave LDS (b64 packed, ~2-way = free), read as B-frags
#pragma unroll
        for (int t = 0; t < 4; ++t) {
            half4 pk;
#pragma unroll
            for (int r = 0; r < 4; ++r) pk[r] = (f16)sf[t][r];
            *(half4*)(Pw + n16 * PSTRIDE + t * 16 + quad * 4) = pk;
        }
        __asm__ volatile("s_waitcnt lgkmcnt(0)" ::: "memory");
        half8 bp0 = *(const half8*)(Pw + n16 * PSTRIDE + quad * 8);
        half8 bp1 = *(const half8*)(Pw + n16 * PSTRIDE + 32 + quad * 8);

        // O^T += V^T P^T
#pragma unroll
        for (int ct = 0; ct < 4; ++ct)
            oacc[ct] = __builtin_amdgcn_mfma_f32_16x16x32_f16(av0[ct], bp0, oacc[ct], 0, 0, 0);
#pragma unroll
        for (int ct = 0; ct < 4; ++ct)
            oacc[ct] = __builtin_amdgcn_mfma_f32_16x16x32_f16(av1[ct], bp1, oacc[ct], 0, 0, 0);
    }

    // fold per-lane l partials (same m across the 4 lanes of a query)
    float l_run = l_loc;
    l_run += __shfl_xor(l_run, 16, 64);
    l_run += __shfl_xor(l_run, 32, 64);

    __syncthreads();
    if (ks > 0) {
        if (quad == 0) {
            MLs[qsub][ks][n16][0] = m_run;
            MLs[qsub][ks][n16][1] = l_run;
        }
        half8 p0, p1;
#pragma unroll
        for (int i = 0; i < 4; ++i) {
            p0[i]     = (f16)oacc[0][i];
            p0[4 + i] = (f16)oacc[1][i];
            p1[i]     = (f16)oacc[2][i];
            p1[4 + i] = (f16)oacc[3][i];
        }
        *(half8*)(&Obuf[qsub][ks - 1][lane][0]) = p0;
        *(half8*)(&Obuf[qsub][ks - 1][lane][8]) = p1;
    }
    __syncthreads();
    if (ks == 0) {
        float m = m_run, l = l_run;
        float o[16];
#pragma unroll
        for (int ct = 0; ct < 4; ++ct)
#pragma unroll
            for (int r = 0; r < 4; ++r) o[ct * 4 + r] = oacc[ct][r];
#pragma unroll
        for (int p = 1; p < 4; ++p) {
            const float mp = MLs[qsub][p][n16][0];
            const float lp = MLs[qsub][p][n16][1];
            half8 q0 = *(const half8*)(&Obuf[qsub][p - 1][lane][0]);
            half8 q1 = *(const half8*)(&Obuf[qsub][p - 1][lane][8]);
            const float mn = fmaxf(m, mp);
            const float a1 = __expf(m - mn);
            const float a2 = __expf(mp - mn);
#pragma unroll
            for (int i = 0; i < 8; ++i) {
                o[i]     = o[i] * a1 + (float)q0[i] * a2;
                o[8 + i] = o[8 + i] * a1 + (float)q1[i] * a2;
            }
            l = l * a1 + lp * a2;
            m = mn;
        }
        const float scale = gptr[0] / l;
#pragma unroll
        for (int ct = 0; ct < 4; ++ct) {
            const size_t idx = (bN + q) * CC + ct * 16 + quad * 4;
            float4 xr = *(const float4*)(x + idx);
            float4 res;
            res.x = o[ct * 4 + 0] * scale + xr.x;
            res.y = o[ct * 4 + 1] * scale + xr.y;
            res.z = o[ct * 4 + 2] * scale + xr.z;
            res.w = o[ct * 4 + 3] * scale + xr.w;
            *(float4*)(out + idx) = res;
        }
    }
}

extern "C" void kernel_launch(void* const* d_in, const int* in_sizes, int n_in,
                              void* d_out, int out_size, void* d_ws, size_t ws_size,
                              hipStream_t stream) {
    const float* x     = (const float*)d_in[0];
    const float* wq    = (const float*)d_in[1];
    const float* bq    = (const float*)d_in[2];
    const float* wk    = (const float*)d_in[3];
    const float* bk    = (const float*)d_in[4];
    const float* wv    = (const float*)d_in[5];
    const float* bv    = (const float*)d_in[6];
    const float* gamma = (const float*)d_in[7];
    float* out = (float*)d_out;

    f16* Qh = (f16*)d_ws;
    f16* Kh = Qh + (size_t)BB * NN * 8;
    f16* VT = Kh + (size_t)BB * NN * 8;

    proj_all_kernel<<<512, 256, 0, stream>>>(x, wq, bq, wk, bk, wv, bv, Qh, Kh, VT);
    attn_kernel<<<BB * 128, 512, 0, stream>>>(Qh, Kh, VT, x, gamma, out);
}

// Round 5
// 210.675 us; speedup vs baseline: 1.5210x; 1.5210x over previous
//
#include <hip/hip_runtime.h>
#include <hip/hip_bf16.h>

// ConvSelfAttn: B=8, N=4096, C=64, d=8. FP32 I/O.
// R5: spill fix. 256-thr blocks (4 waves, key-split-4, 16 q/block), grid 2048.
// S-MFMA = 16x16x16f16 (2-reg frags), staged V halves + cross-iter prefetch,
// exp2-domain softmax (Q pre-scaled by log2e in proj), launch_bounds(256,5),
// batch-pinned-to-XCD block swizzle.

#define BB 8
#define NN 4096
#define CC 64
#define PSTRIDE 72
#define LOG2E 1.44269504088896f

typedef _Float16 f16;
typedef _Float16 half8 __attribute__((ext_vector_type(8)));
typedef _Float16 half4 __attribute__((ext_vector_type(4)));
typedef float floatx4 __attribute__((ext_vector_type(4)));

// ---------------- fused projection (MFMA): Q,K,V^T ----------------
// grid 512 x 256. Q path (weights+bias) pre-scaled by log2e.
__global__ __launch_bounds__(256) void proj_all_kernel(
    const float* __restrict__ x,
    const float* __restrict__ wq, const float* __restrict__ bq,
    const float* __restrict__ wk, const float* __restrict__ bk,
    const float* __restrict__ wv, const float* __restrict__ bv,
    f16* __restrict__ Qh, f16* __restrict__ Kh, f16* __restrict__ VT)
{
    __shared__ alignas(16) f16 Ws[80][PSTRIDE];  // rows 0-63=V, 64-71=Q, 72-79=K
    __shared__ float Bs[80];
    const int tid = threadIdx.x;

    for (int i = tid; i < 4096; i += 256) {
        int cin = i >> 6, cout = i & 63;
        Ws[cout][cin] = (f16)wv[i];
    }
    for (int i = tid; i < 512; i += 256) {
        int cin = i >> 3, c = i & 7;
        Ws[64 + c][cin] = (f16)(wq[i] * LOG2E);
        Ws[72 + c][cin] = (f16)wk[i];
    }
    if (tid < 80)
        Bs[tid] = (tid < 64) ? bv[tid]
                : (tid < 72 ? bq[tid - 64] * LOG2E : bk[tid - 72]);
    __syncthreads();

    const int wave = tid >> 6, lane = tid & 63;
    const int quad = lane >> 4, n16 = lane & 15;
    const long p0 = (long)blockIdx.x * 64 + wave * 16;

    half8 ax[2];
#pragma unroll
    for (int kh = 0; kh < 2; ++kh) {
        const float* xp = x + (p0 + n16) * 64 + kh * 32 + quad * 8;
        float4 x1 = *(const float4*)xp;
        float4 x2 = *(const float4*)(xp + 4);
        ax[kh][0] = (f16)x1.x; ax[kh][1] = (f16)x1.y;
        ax[kh][2] = (f16)x1.z; ax[kh][3] = (f16)x1.w;
        ax[kh][4] = (f16)x2.x; ax[kh][5] = (f16)x2.y;
        ax[kh][6] = (f16)x2.z; ax[kh][7] = (f16)x2.w;
    }

    const int b   = (int)(p0 >> 12);
    const int nn0 = (int)(p0 & 4095);
#pragma unroll
    for (int ct = 0; ct < 5; ++ct) {
        const int cout = (ct < 4) ? ct * 16 + n16 : 64 + n16;
        const float bias = Bs[cout];
        half8 b0 = *(const half8*)(&Ws[cout][quad * 8]);
        half8 b1 = *(const half8*)(&Ws[cout][32 + quad * 8]);
        floatx4 acc = {bias, bias, bias, bias};
        acc = __builtin_amdgcn_mfma_f32_16x16x32_f16(ax[0], b0, acc, 0, 0, 0);
        acc = __builtin_amdgcn_mfma_f32_16x16x32_f16(ax[1], b1, acc, 0, 0, 0);
        if (ct < 4) {
            half4 pk;
#pragma unroll
            for (int r = 0; r < 4; ++r) pk[r] = (f16)acc[r];
            *(half4*)(VT + ((size_t)(b * 64 + ct * 16 + n16)) * NN + nn0 + quad * 4) = pk;
        } else {
            f16* dst = (n16 < 8) ? (Qh + (p0 + quad * 4) * 8 + n16)
                                 : (Kh + (p0 + quad * 4) * 8 + (n16 - 8));
#pragma unroll
            for (int r = 0; r < 4; ++r) dst[r * 8] = (f16)acc[r];
        }
    }
}

// ---------------- flash attention, S^T form ----------------
// grid B*256 = 2048 x 256 thr; wave = ks (0..3): 1024 keys, 16 iters of 64.
__global__ __launch_bounds__(256, 5) void attn_kernel(
    const f16* __restrict__ Qh, const f16* __restrict__ Kh,
    const f16* __restrict__ VT,
    const float* __restrict__ x, const float* __restrict__ gptr,
    float* __restrict__ out)
{
    __shared__ alignas(16) f16 Pbuf[4 * 16 * PSTRIDE];   // 9.2 KB
    __shared__ alignas(16) f16 Obuf[3][64][16];          // 6 KB
    __shared__ float MLs[4][16][2];

    const int tid  = threadIdx.x;
    const int wave = tid >> 6, lane = tid & 63;
    const int quad = lane >> 4, n16 = lane & 15;
    const int ks = wave;

    const int b  = blockIdx.x & 7;        // batch pinned to XCD
    const int qt = blockIdx.x >> 3;
    const int q  = qt * 16 + n16;
    const size_t bN = (size_t)b * NN;

    // Q B-frag for 16x16x16: B[k=quad*4+j][n=n16]; quads 0-1 real (d=8)
    half4 bq4 = {0, 0, 0, 0};
    if (quad < 2) bq4 = *(const half4*)(Qh + (bN + q) * 8 + quad * 4);

    floatx4 oacc[4];
#pragma unroll
    for (int ct = 0; ct < 4; ++ct) oacc[ct] = (floatx4){0.f, 0.f, 0.f, 0.f};
    float m_run = -1e30f, l_loc = 0.f;

    const f16* kptr  = Kh + (bN + (size_t)ks * 1024) * 8;
    const f16* vbase = VT + (size_t)b * 64 * NN + (size_t)ks * 1024;
    const floatx4 zero4 = {0.f, 0.f, 0.f, 0.f};
    f16* Pw = Pbuf + wave * 16 * PSTRIDE;

    // prefetch first V half of iter 0
    half8 av0[4];
#pragma unroll
    for (int ct = 0; ct < 4; ++ct)
        av0[ct] = *(const half8*)(vbase + (size_t)(ct * 16 + n16) * NN + quad * 8);

    for (int it = 0; it < 16; ++it) {
        const int k0 = it * 64;
        // K A-frags (16x16x16): A[m=key][k=quad*4+j], quads 0-1 real
        half4 ak[4];
#pragma unroll
        for (int t = 0; t < 4; ++t)
#pragma unroll
            for (int j = 0; j < 4; ++j) ak[t][j] = (f16)0.f;
        if (quad < 2) {
#pragma unroll
            for (int t = 0; t < 4; ++t)
                ak[t] = *(const half4*)(kptr + (k0 + t * 16 + n16) * 8 + quad * 4);
        }
        floatx4 sf[4];
#pragma unroll
        for (int t = 0; t < 4; ++t)
            sf[t] = __builtin_amdgcn_mfma_f32_16x16x16f16(ak[t], bq4, zero4, 0, 0, 0);

        // softmax in exp2 domain (Q pre-scaled by log2e)
        float mx = sf[0][0];
#pragma unroll
        for (int t = 0; t < 4; ++t)
#pragma unroll
            for (int r = 0; r < 4; ++r) mx = fmaxf(mx, sf[t][r]);
        mx = fmaxf(mx, __shfl_xor(mx, 16, 64));
        mx = fmaxf(mx, __shfl_xor(mx, 32, 64));
        const float mnew = fmaxf(m_run, mx);
        const float alpha = __builtin_exp2f(m_run - mnew);
        m_run = mnew;
        float rs = 0.f;
#pragma unroll
        for (int t = 0; t < 4; ++t)
#pragma unroll
            for (int r = 0; r < 4; ++r) {
                float pv = __builtin_exp2f(sf[t][r] - mnew);
                sf[t][r] = pv;
                rs += pv;
            }
        l_loc = l_loc * alpha + rs;
#pragma unroll
        for (int ct = 0; ct < 4; ++ct) oacc[ct] *= alpha;

        // issue second V half before LDS round-trip
        half8 av1[4];
#pragma unroll
        for (int ct = 0; ct < 4; ++ct)
            av1[ct] = *(const half8*)(vbase + (size_t)(ct * 16 + n16) * NN
                                      + k0 + 32 + quad * 8);

        // P^T -> per-wave LDS, read back as x32 B-frags
#pragma unroll
        for (int t = 0; t < 4; ++t) {
            half4 pk;
#pragma unroll
            for (int r = 0; r < 4; ++r) pk[r] = (f16)sf[t][r];
            *(half4*)(Pw + n16 * PSTRIDE + t * 16 + quad * 4) = pk;
        }
        __asm__ volatile("s_waitcnt lgkmcnt(0)" ::: "memory");
        half8 bp0 = *(const half8*)(Pw + n16 * PSTRIDE + quad * 8);
        half8 bp1 = *(const half8*)(Pw + n16 * PSTRIDE + 32 + quad * 8);

        // O^T += V^T P^T (first half), then prefetch next iter's first half
#pragma unroll
        for (int ct = 0; ct < 4; ++ct)
            oacc[ct] = __builtin_amdgcn_mfma_f32_16x16x32_f16(av0[ct], bp0, oacc[ct], 0, 0, 0);
        if (it < 15) {
#pragma unroll
            for (int ct = 0; ct < 4; ++ct)
                av0[ct] = *(const half8*)(vbase + (size_t)(ct * 16 + n16) * NN
                                          + k0 + 64 + quad * 8);
        }
#pragma unroll
        for (int ct = 0; ct < 4; ++ct)
            oacc[ct] = __builtin_amdgcn_mfma_f32_16x16x32_f16(av1[ct], bp1, oacc[ct], 0, 0, 0);
    }

    // fold per-lane l partials (lanes ^16,^32 share the query)
    float l_run = l_loc;
    l_run += __shfl_xor(l_run, 16, 64);
    l_run += __shfl_xor(l_run, 32, 64);

    __syncthreads();
    if (ks > 0) {
        if (quad == 0) {
            MLs[ks][n16][0] = m_run;
            MLs[ks][n16][1] = l_run;
        }
        half8 p0, p1;
#pragma unroll
        for (int i = 0; i < 4; ++i) {
            p0[i]     = (f16)oacc[0][i];
            p0[4 + i] = (f16)oacc[1][i];
            p1[i]     = (f16)oacc[2][i];
            p1[4 + i] = (f16)oacc[3][i];
        }
        *(half8*)(&Obuf[ks - 1][lane][0]) = p0;
        *(half8*)(&Obuf[ks - 1][lane][8]) = p1;
    }
    __syncthreads();
    if (ks == 0) {
        float m = m_run, l = l_run;
        float o[16];
#pragma unroll
        for (int ct = 0; ct < 4; ++ct)
#pragma unroll
            for (int r = 0; r < 4; ++r) o[ct * 4 + r] = oacc[ct][r];
#pragma unroll
        for (int p = 1; p < 4; ++p) {
            const float mp = MLs[p][n16][0];
            const float lp = MLs[p][n16][1];
            half8 q0 = *(const half8*)(&Obuf[p - 1][lane][0]);
            half8 q1 = *(const half8*)(&Obuf[p - 1][lane][8]);
            const float mn = fmaxf(m, mp);
            const float a1 = __builtin_exp2f(m - mn);
            const float a2 = __builtin_exp2f(mp - mn);
#pragma unroll
            for (int i = 0; i < 8; ++i) {
                o[i]     = o[i] * a1 + (float)q0[i] * a2;
                o[8 + i] = o[8 + i] * a1 + (float)q1[i] * a2;
            }
            l = l * a1 + lp * a2;
            m = mn;
        }
        const float scale = gptr[0] / l;
#pragma unroll
        for (int ct = 0; ct < 4; ++ct) {
            const size_t idx = (bN + q) * CC + ct * 16 + quad * 4;
            float4 xr = *(const float4*)(x + idx);
            float4 res;
            res.x = o[ct * 4 + 0] * scale + xr.x;
            res.y = o[ct * 4 + 1] * scale + xr.y;
            res.z = o[ct * 4 + 2] * scale + xr.z;
            res.w = o[ct * 4 + 3] * scale + xr.w;
            *(float4*)(out + idx) = res;
        }
    }
}

extern "C" void kernel_launch(void* const* d_in, const int* in_sizes, int n_in,
                              void* d_out, int out_size, void* d_ws, size_t ws_size,
                              hipStream_t stream) {
    const float* x     = (const float*)d_in[0];
    const float* wq    = (const float*)d_in[1];
    const float* bq    = (const float*)d_in[2];
    const float* wk    = (const float*)d_in[3];
    const float* bk    = (const float*)d_in[4];
    const float* wv    = (const float*)d_in[5];
    const float* bv    = (const float*)d_in[6];
    const float* gamma = (const float*)d_in[7];
    float* out = (float*)d_out;

    f16* Qh = (f16*)d_ws;
    f16* Kh = Qh + (size_t)BB * NN * 8;
    f16* VT = Kh + (size_t)BB * NN * 8;

    proj_all_kernel<<<512, 256, 0, stream>>>(x, wq, bq, wk, bk, wv, bv, Qh, Kh, VT);
    attn_kernel<<<BB * 256, 256, 0, stream>>>(Qh, Kh, VT, x, gamma, out);
}

// Round 6
// 131.634 us; speedup vs baseline: 2.4343x; 1.6005x over previous
//
#include <hip/hip_runtime.h>
#include <hip/hip_bf16.h>

// ConvSelfAttn: B=8, N=4096, C=64, d=8. FP32 I/O.
// R6: fragment-major K/V workspace layouts (all attn global loads fully
// coalesced), 32 queries/wave (2 q-subtiles amortize each V read), 65k
// wave-iters (was 131k). Proj repacks V/K via LDS (conflict-free strides).

#define BB 8
#define NN 4096
#define CC 64
#define PSTRIDE 72
#define LOG2E 1.44269504088896f

typedef _Float16 f16;
typedef _Float16 half8 __attribute__((ext_vector_type(8)));
typedef _Float16 half4 __attribute__((ext_vector_type(4)));
typedef float floatx4 __attribute__((ext_vector_type(4)));

// ws layouts (halfs):
//   Qh    [B*N][8]                      row-major, Q pre-scaled by log2e
//   Kfrag [B][256 kblk][32 lane][4]     A-frag for 16x16x16 (quads 0-1 only)
//   Vfrag [B][128 kb32][4 ct][64 lane][8]  A-frag for 16x16x32 PV

// ---------------- fused projection + fragment repack ----------------
// grid 512 x 256 (4 waves x 16 pixels; block = 64 pixels of one batch)
__global__ __launch_bounds__(256) void proj_all_kernel(
    const float* __restrict__ x,
    const float* __restrict__ wq, const float* __restrict__ bq,
    const float* __restrict__ wk, const float* __restrict__ bk,
    const float* __restrict__ wv, const float* __restrict__ bv,
    f16* __restrict__ Qh, f16* __restrict__ Kf, f16* __restrict__ Vf)
{
    __shared__ alignas(16) f16 Ws[80][PSTRIDE];  // rows 0-63=V, 64-71=Q, 72-79=K
    __shared__ float Bs[80];
    __shared__ alignas(16) f16 Vs[64][66];       // [pixel][ch], pitch 66
    __shared__ alignas(16) f16 Ks[64][12];       // [pixel][ch], pitch 12
    const int tid = threadIdx.x;

    for (int i = tid; i < 4096; i += 256) {
        int cin = i >> 6, cout = i & 63;
        Ws[cout][cin] = (f16)wv[i];
    }
    for (int i = tid; i < 512; i += 256) {
        int cin = i >> 3, c = i & 7;
        Ws[64 + c][cin] = (f16)(wq[i] * LOG2E);
        Ws[72 + c][cin] = (f16)wk[i];
    }
    if (tid < 80)
        Bs[tid] = (tid < 64) ? bv[tid]
                : (tid < 72 ? bq[tid - 64] * LOG2E : bk[tid - 72]);
    __syncthreads();

    const int wave = tid >> 6, lane = tid & 63;
    const int quad = lane >> 4, n16 = lane & 15;
    const long pb = (long)blockIdx.x * 64;        // block's first pixel (global)
    const long p0 = pb + wave * 16;               // wave's first pixel
    const int  b   = (int)(pb >> 12);
    const int  nnb = (int)(pb & 4095);            // within-batch pixel base

    half8 ax[2];
#pragma unroll
    for (int kh = 0; kh < 2; ++kh) {
        const float* xp = x + (p0 + n16) * 64 + kh * 32 + quad * 8;
        float4 x1 = *(const float4*)xp;
        float4 x2 = *(const float4*)(xp + 4);
        ax[kh][0] = (f16)x1.x; ax[kh][1] = (f16)x1.y;
        ax[kh][2] = (f16)x1.z; ax[kh][3] = (f16)x1.w;
        ax[kh][4] = (f16)x2.x; ax[kh][5] = (f16)x2.y;
        ax[kh][6] = (f16)x2.z; ax[kh][7] = (f16)x2.w;
    }

#pragma unroll
    for (int ct = 0; ct < 5; ++ct) {
        const int cout = (ct < 4) ? ct * 16 + n16 : 64 + n16;
        const float bias = Bs[cout];
        half8 b0 = *(const half8*)(&Ws[cout][quad * 8]);
        half8 b1 = *(const half8*)(&Ws[cout][32 + quad * 8]);
        floatx4 acc = {bias, bias, bias, bias};
        acc = __builtin_amdgcn_mfma_f32_16x16x32_f16(ax[0], b0, acc, 0, 0, 0);
        acc = __builtin_amdgcn_mfma_f32_16x16x32_f16(ax[1], b1, acc, 0, 0, 0);
        if (ct < 4) {
            // D[m=pixel=quad*4+r][n=ch=n16] -> LDS staging tile
#pragma unroll
            for (int r = 0; r < 4; ++r)
                Vs[wave * 16 + quad * 4 + r][ct * 16 + n16] = (f16)acc[r];
        } else if (n16 < 8) {
            f16* dst = Qh + (p0 + quad * 4) * 8 + n16;
#pragma unroll
            for (int r = 0; r < 4; ++r) dst[r * 8] = (f16)acc[r];
        } else {
#pragma unroll
            for (int r = 0; r < 4; ++r)
                Ks[wave * 16 + quad * 4 + r][n16 - 8] = (f16)acc[r];
        }
    }
    __syncthreads();

    // V fragment stores: 8 tiles (kb in {0,1} x ct in {0..3}); 2 per wave.
#pragma unroll
    for (int u = 0; u < 2; ++u) {
        const int tt = wave * 2 + u;
        const int kb = tt >> 2, ct = tt & 3;
        half8 v;
#pragma unroll
        for (int j = 0; j < 8; ++j)
            v[j] = Vs[kb * 32 + quad * 8 + j][ct * 16 + n16];
        const size_t kbg = (size_t)b * 128 + (nnb >> 5) + kb;
        *(half8*)(Vf + (kbg * 4 + ct) * 512 + lane * 8) = v;
    }
    // K fragment store: kblk = wave; only quads 0-1 (32 lanes) store.
    if (quad < 2) {
        half4 kv;
#pragma unroll
        for (int j = 0; j < 4; ++j)
            kv[j] = Ks[wave * 16 + n16][quad * 4 + j];
        const size_t kbg = (size_t)b * 256 + (nnb >> 4) + wave;
        *(half4*)(Kf + kbg * 128 + lane * 4) = kv;
    }
}

// ---------------- flash attention, S^T form, 32 q/wave ----------------
// grid B*128 = 1024 x 256 thr; wave = ks (0..3): keys [ks*1024,+1024), 16 iters.
__global__ __launch_bounds__(256, 4) void attn_kernel(
    const f16* __restrict__ Qh, const f16* __restrict__ Kf,
    const f16* __restrict__ Vf,
    const float* __restrict__ x, const float* __restrict__ gptr,
    float* __restrict__ out)
{
    __shared__ alignas(16) f16 Pbuf[4 * 2 * 16 * PSTRIDE];  // 18.4 KB
    __shared__ alignas(16) f16 Obuf[3][2][64][16];          // 12.3 KB
    __shared__ float MLs[4][2][16][2];                      // 1 KB

    const int tid  = threadIdx.x;
    const int wave = tid >> 6, lane = tid & 63;
    const int quad = lane >> 4, n16 = lane & 15;
    const int ks = wave;

    const int b  = blockIdx.x & 7;        // batch pinned for L2 locality
    const int qt = blockIdx.x >> 3;       // 0..127 (32-query tile)
    const size_t bN = (size_t)b * NN;

    // Q B-frags (16x16x16): quads 0-1 real, zeros persist elsewhere
    half4 bq4[2];
#pragma unroll
    for (int qt2 = 0; qt2 < 2; ++qt2) {
#pragma unroll
        for (int j = 0; j < 4; ++j) bq4[qt2][j] = (f16)0.f;
        if (quad < 2)
            bq4[qt2] = *(const half4*)(Qh + (bN + qt * 32 + qt2 * 16 + n16) * 8 + quad * 4);
    }
    half4 ak[4];
#pragma unroll
    for (int t = 0; t < 4; ++t)
#pragma unroll
        for (int j = 0; j < 4; ++j) ak[t][j] = (f16)0.f;

    floatx4 oacc[2][4];
#pragma unroll
    for (int qt2 = 0; qt2 < 2; ++qt2)
#pragma unroll
        for (int ct = 0; ct < 4; ++ct) oacc[qt2][ct] = (floatx4){0.f, 0.f, 0.f, 0.f};
    float m_run[2] = {-1e30f, -1e30f}, l_loc[2] = {0.f, 0.f};

    const f16* kfb = Kf + ((size_t)b * 256 + ks * 64) * 128;
    const f16* vfb = Vf + ((size_t)b * 128 + ks * 32) * 2048;
    const floatx4 zero4 = {0.f, 0.f, 0.f, 0.f};
    f16* Pw0 = Pbuf + (wave * 2 + 0) * 16 * PSTRIDE;
    f16* Pw1 = Pbuf + (wave * 2 + 1) * 16 * PSTRIDE;

    for (int it = 0; it < 16; ++it) {
        // K frags: contiguous 256B per tile (quads 0-1)
        if (quad < 2) {
#pragma unroll
            for (int t = 0; t < 4; ++t)
                ak[t] = *(const half4*)(kfb + (it * 4 + t) * 128 + lane * 4);
        }
        // V first half: contiguous 1KB per ct
        half8 av0[4];
#pragma unroll
        for (int ct = 0; ct < 4; ++ct)
            av0[ct] = *(const half8*)(vfb + ((size_t)(it * 2) * 4 + ct) * 512 + lane * 8);

        // ---- q-subtile 0: S, softmax, P write ----
        floatx4 sf[4];
#pragma unroll
        for (int t = 0; t < 4; ++t)
            sf[t] = __builtin_amdgcn_mfma_f32_16x16x16f16(ak[t], bq4[0], zero4, 0, 0, 0);

        // V second half: issue under softmax0
        half8 av1[4];
#pragma unroll
        for (int ct = 0; ct < 4; ++ct)
            av1[ct] = *(const half8*)(vfb + ((size_t)(it * 2 + 1) * 4 + ct) * 512 + lane * 8);

#pragma unroll
        for (int qt2 = 0; qt2 < 2; ++qt2) {
            if (qt2 == 1) {
#pragma unroll
                for (int t = 0; t < 4; ++t)
                    sf[t] = __builtin_amdgcn_mfma_f32_16x16x16f16(ak[t], bq4[1], zero4, 0, 0, 0);
            }
            float mx = sf[0][0];
#pragma unroll
            for (int t = 0; t < 4; ++t)
#pragma unroll
                for (int r = 0; r < 4; ++r) mx = fmaxf(mx, sf[t][r]);
            mx = fmaxf(mx, __shfl_xor(mx, 16, 64));
            mx = fmaxf(mx, __shfl_xor(mx, 32, 64));
            const float mnew = fmaxf(m_run[qt2], mx);
            const float alpha = __builtin_exp2f(m_run[qt2] - mnew);
            m_run[qt2] = mnew;
            float rs = 0.f;
#pragma unroll
            for (int t = 0; t < 4; ++t)
#pragma unroll
                for (int r = 0; r < 4; ++r) {
                    float pv = __builtin_exp2f(sf[t][r] - mnew);
                    sf[t][r] = pv;
                    rs += pv;
                }
            l_loc[qt2] = l_loc[qt2] * alpha + rs;
#pragma unroll
            for (int ct = 0; ct < 4; ++ct) oacc[qt2][ct] *= alpha;
            f16* Pw = qt2 ? Pw1 : Pw0;
#pragma unroll
            for (int t = 0; t < 4; ++t) {
                half4 pk;
#pragma unroll
                for (int r = 0; r < 4; ++r) pk[r] = (f16)sf[t][r];
                *(half4*)(Pw + n16 * PSTRIDE + t * 16 + quad * 4) = pk;
            }
        }
        __asm__ volatile("s_waitcnt lgkmcnt(0)" ::: "memory");

        // ---- PV: O^T += V^T P^T, both halves x both q-subtiles ----
#pragma unroll
        for (int qt2 = 0; qt2 < 2; ++qt2) {
            f16* Pw = qt2 ? Pw1 : Pw0;
            half8 bp0 = *(const half8*)(Pw + n16 * PSTRIDE + quad * 8);
            half8 bp1 = *(const half8*)(Pw + n16 * PSTRIDE + 32 + quad * 8);
#pragma unroll
            for (int ct = 0; ct < 4; ++ct)
                oacc[qt2][ct] = __builtin_amdgcn_mfma_f32_16x16x32_f16(av0[ct], bp0, oacc[qt2][ct], 0, 0, 0);
#pragma unroll
            for (int ct = 0; ct < 4; ++ct)
                oacc[qt2][ct] = __builtin_amdgcn_mfma_f32_16x16x32_f16(av1[ct], bp1, oacc[qt2][ct], 0, 0, 0);
        }
    }

    // fold per-lane l partials (quads share query via ^16, ^32)
    float l_run[2];
#pragma unroll
    for (int qt2 = 0; qt2 < 2; ++qt2) {
        float l = l_loc[qt2];
        l += __shfl_xor(l, 16, 64);
        l += __shfl_xor(l, 32, 64);
        l_run[qt2] = l;
    }

    __syncthreads();
    if (ks > 0) {
#pragma unroll
        for (int qt2 = 0; qt2 < 2; ++qt2) {
            if (quad == 0) {
                MLs[ks][qt2][n16][0] = m_run[qt2];
                MLs[ks][qt2][n16][1] = l_run[qt2];
            }
            half8 p0, p1;
#pragma unroll
            for (int i = 0; i < 4; ++i) {
                p0[i]     = (f16)oacc[qt2][0][i];
                p0[4 + i] = (f16)oacc[qt2][1][i];
                p1[i]     = (f16)oacc[qt2][2][i];
                p1[4 + i] = (f16)oacc[qt2][3][i];
            }
            *(half8*)(&Obuf[ks - 1][qt2][lane][0]) = p0;
            *(half8*)(&Obuf[ks - 1][qt2][lane][8]) = p1;
        }
    }
    __syncthreads();
    if (ks == 0) {
        const float g = gptr[0];
#pragma unroll
        for (int qt2 = 0; qt2 < 2; ++qt2) {
            float m = m_run[qt2], l = l_run[qt2];
            float o[16];
#pragma unroll
            for (int ct = 0; ct < 4; ++ct)
#pragma unroll
                for (int r = 0; r < 4; ++r) o[ct * 4 + r] = oacc[qt2][ct][r];
#pragma unroll
            for (int p = 1; p < 4; ++p) {
                const float mp = MLs[p][qt2][n16][0];
                const float lp = MLs[p][qt2][n16][1];
                half8 q0 = *(const half8*)(&Obuf[p - 1][qt2][lane][0]);
                half8 q1 = *(const half8*)(&Obuf[p - 1][qt2][lane][8]);
                const float mn = fmaxf(m, mp);
                const float a1 = __builtin_exp2f(m - mn);
                const float a2 = __builtin_exp2f(mp - mn);
#pragma unroll
                for (int i = 0; i < 8; ++i) {
                    o[i]     = o[i] * a1 + (float)q0[i] * a2;
                    o[8 + i] = o[8 + i] * a1 + (float)q1[i] * a2;
                }
                l = l * a1 + lp * a2;
                m = mn;
            }
            const float scale = g / l;
            const int q = qt * 32 + qt2 * 16 + n16;
#pragma unroll
            for (int ct = 0; ct < 4; ++ct) {
                const size_t idx = (bN + q) * CC + ct * 16 + quad * 4;
                float4 xr = *(const float4*)(x + idx);
                float4 res;
                res.x = o[ct * 4 + 0] * scale + xr.x;
                res.y = o[ct * 4 + 1] * scale + xr.y;
                res.z = o[ct * 4 + 2] * scale + xr.z;
                res.w = o[ct * 4 + 3] * scale + xr.w;
                *(float4*)(out + idx) = res;
            }
        }
    }
}

extern "C" void kernel_launch(void* const* d_in, const int* in_sizes, int n_in,
                              void* d_out, int out_size, void* d_ws, size_t ws_size,
                              hipStream_t stream) {
    const float* x     = (const float*)d_in[0];
    const float* wq    = (const float*)d_in[1];
    const float* bq    = (const float*)d_in[2];
    const float* wk    = (const float*)d_in[3];
    const float* bk    = (const float*)d_in[4];
    const float* wv    = (const float*)d_in[5];
    const float* bv    = (const float*)d_in[6];
    const float* gamma = (const float*)d_in[7];
    float* out = (float*)d_out;

    // ws (halfs): Qh 256K | Kfrag 256K | Vfrag 2M  -> 5 MB total
    f16* Qh = (f16*)d_ws;
    f16* Kf = Qh + (size_t)BB * NN * 8;
    f16* Vf = Kf + (size_t)BB * 256 * 128;

    proj_all_kernel<<<512, 256, 0, stream>>>(x, wq, bq, wk, bk, wv, bv, Qh, Kf, Vf);
    attn_kernel<<<BB * 128, 256, 0, stream>>>(Qh, Kf, Vf, x, gamma, out);
}